// Round 17
// baseline (30.022 us; speedup 1.0000x reference)
//
#include <hip/hip_runtime.h>
#include <hip/hip_bf16.h>

#define NB 128
#define NN 2048
#define DEG 16
#define EMBD 16
#define NL 4
#define OBSD 6154
#define HID 45
#define NOUT 15
#define KS 16
#define CH 385   // ceil(OBSD / KS)
#define RPB 8    // batch rows per mlp1 block (share each oW1 load across 8 rows)
#define LOG2E 1.44269504f
#define MEGAB NB                 // 128 mega blocks (1 per graph)
#define MLPB ((NB / RPB) * KS)   // 256 mlp blocks

__device__ __forceinline__ float frcp(float v) { return __builtin_amdgcn_rcpf(v); }

__device__ __forceinline__ uint32_t pk_bf16(float a, float b) {
    uint32_t ua = __float_as_uint(a); ua += 0x7fffu + ((ua >> 16) & 1u);
    uint32_t ub = __float_as_uint(b); ub += 0x7fffu + ((ub >> 16) & 1u);
    return (ua >> 16) | (ub & 0xffff0000u);
}
__device__ __forceinline__ float lo_bf(uint32_t u) { return __uint_as_float(u << 16); }
__device__ __forceinline__ float hi_bf(uint32_t u) { return __uint_as_float(u & 0xffff0000u); }

__device__ __forceinline__ void ln4(const float* p, const float* g, const float* bb, float* o) {
    float m = 0.25f * (p[0] + p[1] + p[2] + p[3]);
    float var = 0.f;
#pragma unroll
    for (int j = 0; j < 4; ++j) { float d = p[j] - m; var += d * d; }
    var *= 0.25f;
    float rs = rsqrtf(var + 1e-5f);
#pragma unroll
    for (int j = 0; j < 4; ++j) o[j] = g[j] * (p[j] - m) * rs + bb[j];
}

__device__ __forceinline__ void node_tail(float* hh, const float* msg,
    const float* wo, const float* bol, const float* g1, const float* be1,
    const float* w1, const float* b1l, const float* w2, const float* b2l,
    const float* g2, const float* be2)
{
    float pre[4];
#pragma unroll
    for (int j = 0; j < 4; ++j) {
        float s = bol[j];
#pragma unroll
        for (int i = 0; i < 4; ++i) s += msg[i] * wo[i * 4 + j];
        pre[j] = hh[j] + s;
    }
    float hn[4];
    ln4(pre, g1, be1, hn);
    float mid[8];
#pragma unroll
    for (int j = 0; j < 8; ++j) {
        float s = b1l[j];
#pragma unroll
        for (int i = 0; i < 4; ++i) s += hn[i] * w1[i * 8 + j];
        mid[j] = fmaxf(s, 0.f);
    }
    float pre2[4];
#pragma unroll
    for (int j = 0; j < 4; ++j) {
        float s = b2l[j];
#pragma unroll
        for (int i = 0; i < 8; ++i) s += mid[i] * w2[i * 4 + j];
        pre2[j] = hn[j] + s;
    }
    ln4(pre2, g2, be2, hh);
}

__device__ __forceinline__ uint4 kv_pack(const float* hh,
    const float* wk, const float* bkl, const float* wv, const float* bvl)
{
    float kk[4], vv[4];
#pragma unroll
    for (int j = 0; j < 4; ++j) {
        float sk = bkl[j], sv = bvl[j];
#pragma unroll
        for (int i = 0; i < 4; ++i) {
            sk += hh[i] * wk[i * 4 + j];
            sv += hh[i] * wv[i * 4 + j];
        }
        kk[j] = sk; vv[j] = sv;
    }
    return make_uint4(pk_bf16(kk[0], kk[1]), pk_bf16(kk[2], kk[3]),
                      pk_bf16(vv[0], vv[1]), pk_bf16(vv[2], vv[3]));
}

// gather + tail body for a layer (kv staged in LDS, q2 prescaled), 16 edges
__device__ __forceinline__ void gather_tail(const uint4* kv, const int* su,
    const float* q2, float* hh, int l,
    const float* Wo, const float* bo, const float* ln1_g, const float* ln1_b,
    const float* W1, const float* b1, const float* W2, const float* b2,
    const float* ln2_g, const float* ln2_b)
{
    float z[4] = {0.f, 0.f, 0.f, 0.f}, wa[4] = {0.f, 0.f, 0.f, 0.f};
#pragma unroll
    for (int eb = 0; eb < 4; ++eb) {
        uint4 t0 = kv[su[eb * 4 + 0]];
        uint4 t1 = kv[su[eb * 4 + 1]];
        uint4 t2 = kv[su[eb * 4 + 2]];
        uint4 t3 = kv[su[eb * 4 + 3]];
        float p;
        p = __builtin_amdgcn_exp2f(q2[0] * lo_bf(t0.x)); z[0] += p; wa[0] += p * lo_bf(t0.z);
        p = __builtin_amdgcn_exp2f(q2[1] * hi_bf(t0.x)); z[1] += p; wa[1] += p * hi_bf(t0.z);
        p = __builtin_amdgcn_exp2f(q2[2] * lo_bf(t0.y)); z[2] += p; wa[2] += p * lo_bf(t0.w);
        p = __builtin_amdgcn_exp2f(q2[3] * hi_bf(t0.y)); z[3] += p; wa[3] += p * hi_bf(t0.w);
        p = __builtin_amdgcn_exp2f(q2[0] * lo_bf(t1.x)); z[0] += p; wa[0] += p * lo_bf(t1.z);
        p = __builtin_amdgcn_exp2f(q2[1] * hi_bf(t1.x)); z[1] += p; wa[1] += p * hi_bf(t1.z);
        p = __builtin_amdgcn_exp2f(q2[2] * lo_bf(t1.y)); z[2] += p; wa[2] += p * lo_bf(t1.w);
        p = __builtin_amdgcn_exp2f(q2[3] * hi_bf(t1.y)); z[3] += p; wa[3] += p * hi_bf(t1.w);
        p = __builtin_amdgcn_exp2f(q2[0] * lo_bf(t2.x)); z[0] += p; wa[0] += p * lo_bf(t2.z);
        p = __builtin_amdgcn_exp2f(q2[1] * hi_bf(t2.x)); z[1] += p; wa[1] += p * hi_bf(t2.z);
        p = __builtin_amdgcn_exp2f(q2[2] * lo_bf(t2.y)); z[2] += p; wa[2] += p * lo_bf(t2.w);
        p = __builtin_amdgcn_exp2f(q2[3] * hi_bf(t2.y)); z[3] += p; wa[3] += p * hi_bf(t2.w);
        p = __builtin_amdgcn_exp2f(q2[0] * lo_bf(t3.x)); z[0] += p; wa[0] += p * lo_bf(t3.z);
        p = __builtin_amdgcn_exp2f(q2[1] * hi_bf(t3.x)); z[1] += p; wa[1] += p * hi_bf(t3.z);
        p = __builtin_amdgcn_exp2f(q2[2] * lo_bf(t3.y)); z[2] += p; wa[2] += p * lo_bf(t3.w);
        p = __builtin_amdgcn_exp2f(q2[3] * hi_bf(t3.y)); z[3] += p; wa[3] += p * hi_bf(t3.w);
    }
    float msg[4];
#pragma unroll
    for (int j = 0; j < 4; ++j) msg[j] = wa[j] * frcp(z[j] + 1e-6f);
    node_tail(hh, msg, Wo + l * 16, bo + l * 4, ln1_g + l * 4, ln1_b + l * 4,
              W1 + l * 32, b1 + l * 8, W2 + l * 32, b2 + l * 4,
              ln2_g + l * 4, ln2_b + l * 4);
}

// mlp1 split-K block body (1024 threads, 16 waves); red = [16][RPB][HID] floats (23 KB)
__device__ __forceinline__ void mlp1_block(int mb, int tid,
    const float* __restrict__ obs, const float* __restrict__ oW1,
    float* __restrict__ partial, float* red)
{
    const int rg = mb >> 4;
    const int ks = mb & (KS - 1);
    const int w = tid >> 6, lane = tid & 63;
    const int c0 = ks * CH;
    const int c1 = min(c0 + CH, OBSD);
    const int wl = (c1 - c0 + 15) >> 4;
    const int s0 = c0 + w * wl;
    const int s1 = min(s0 + wl, c1);
    const float* ob0 = obs + (size_t)(rg * RPB) * OBSD;

    if (lane < HID) {
        float acc[RPB] = {0.f, 0.f, 0.f, 0.f, 0.f, 0.f, 0.f, 0.f};
        for (int i = s0; i < s1; ++i) {
            float wv = oW1[(size_t)(i + 4) * HID + lane];
#pragma unroll
            for (int r = 0; r < RPB; ++r)
                acc[r] += ob0[(size_t)r * OBSD + i] * wv;
        }
#pragma unroll
        for (int r = 0; r < RPB; ++r) red[(w * RPB + r) * HID + lane] = acc[r];
    }
    __syncthreads();
    for (int idx = tid; idx < RPB * HID; idx += 1024) {
        const int r = idx / HID, j = idx % HID;
        float s = 0.f;
#pragma unroll
        for (int ww = 0; ww < 16; ++ww) s += red[(ww * RPB + r) * HID + j];
        partial[(size_t)((rg * RPB + r) * KS + ks) * HID + j] = s;
    }
}

// ===== K1: blocks [0,128): full GAT per graph in LDS; [128,384): mlp1 split-K =====
__global__ __launch_bounds__(1024) void fused_kernel(
    const float* __restrict__ x, const int* __restrict__ src,
    const int* __restrict__ agent_nodes,
    const float* __restrict__ obs, const float* __restrict__ oW1,
    float* __restrict__ partial, float* __restrict__ gat_out,
    const float* __restrict__ We, const float* __restrict__ be,
    const float* __restrict__ Wq, const float* __restrict__ bq,
    const float* __restrict__ Wk, const float* __restrict__ bk,
    const float* __restrict__ Wv, const float* __restrict__ bv,
    const float* __restrict__ Wo, const float* __restrict__ bo,
    const float* __restrict__ ln1_g, const float* __restrict__ ln1_b,
    const float* __restrict__ W1, const float* __restrict__ b1,
    const float* __restrict__ W2, const float* __restrict__ b2,
    const float* __restrict__ ln2_g, const float* __restrict__ ln2_b)
{
    __shared__ uint4  kvbuf[NN];      // 32 KB: kv0, then reused as kv1. mlp: red overlay
    __shared__ float4 h1lds[NN];      // 32 KB
    __shared__ int    conen[289];
    __shared__ float  h2c[289][4];
    __shared__ float  h3buf[17][4];
    const int bid = blockIdx.x;
    const int tid = threadIdx.x;

    if (bid >= MEGAB) {
        mlp1_block(bid - MEGAB, tid, obs, oW1, partial,
                   reinterpret_cast<float*>(kvbuf));
        return;
    }

    // mega block = the critical path; bias the CU scheduler toward these waves
    __builtin_amdgcn_s_setprio(1);

    const int b = bid;
    const int ag = agent_nodes[b];

    // cone node list (only needs src)
    if (tid < 17)  conen[tid] = (tid < 16) ? src[ag * DEG + tid] : ag;
    if (tid < 272) {
        const int i = tid >> 4, e = tid & 15;
        const int ti = (i < 16) ? src[ag * DEG + i] : ag;
        conen[17 + tid] = src[ti * DEG + e];
    }

    // ---- embed both owned nodes, kv0 -> LDS ----
    float he[2][4];
#pragma unroll
    for (int c = 0; c < 2; ++c) {
        const int n = c * 1024 + tid;
        const float4* xr = reinterpret_cast<const float4*>(
            x + ((size_t)b * NN + n) * EMBD);
        float xv[16];
#pragma unroll
        for (int t4 = 0; t4 < 4; ++t4) {
            float4 t = xr[t4];
            xv[t4 * 4 + 0] = t.x; xv[t4 * 4 + 1] = t.y;
            xv[t4 * 4 + 2] = t.z; xv[t4 * 4 + 3] = t.w;
        }
#pragma unroll
        for (int j = 0; j < 4; ++j) {
            float s = be[j];
#pragma unroll
            for (int i = 0; i < 16; ++i) s += xv[i] * We[i * 4 + j];
            he[c][j] = s;
        }
        kvbuf[n] = kv_pack(he[c], Wk, bk, Wv, bv);   // layer-0 weights
    }
    __syncthreads();

    // ---- L0 for both nodes (h1 into registers) ----
    float h1r[2][4];
#pragma unroll
    for (int u = 0; u < 2; ++u) {
        const int n = u * 1024 + tid;
        float q2[4];
#pragma unroll
        for (int j = 0; j < 4; ++j) {
            float sq = bq[j];
#pragma unroll
            for (int i = 0; i < 4; ++i) sq += he[u][i] * Wq[i * 4 + j];
            q2[j] = sq * LOG2E;
        }
        int su[16];
        const int4* sp = reinterpret_cast<const int4*>(src + n * DEG);
#pragma unroll
        for (int t4 = 0; t4 < 4; ++t4) {
            int4 s4 = sp[t4];
            su[t4 * 4 + 0] = s4.x; su[t4 * 4 + 1] = s4.y;
            su[t4 * 4 + 2] = s4.z; su[t4 * 4 + 3] = s4.w;
        }
        float hh[4] = {he[u][0], he[u][1], he[u][2], he[u][3]};
        gather_tail(kvbuf, su, q2, hh, 0, Wo, bo, ln1_g, ln1_b, W1, b1, W2, b2,
                    ln2_g, ln2_b);
#pragma unroll
        for (int j = 0; j < 4; ++j) h1r[u][j] = hh[j];
    }
    __syncthreads();   // all L0 gathers done -> safe to overwrite kvbuf

    // ---- kv1 overwrites kvbuf; h1 -> LDS ----
    {
        const float* wk1 = Wk + 16; const float* bk1 = bk + 4;
        const float* wv1 = Wv + 16; const float* bv1 = bv + 4;
#pragma unroll
        for (int u = 0; u < 2; ++u) {
            const int n = u * 1024 + tid;
            kvbuf[n] = kv_pack(h1r[u], wk1, bk1, wv1, bv1);
            h1lds[n] = make_float4(h1r[u][0], h1r[u][1], h1r[u][2], h1r[u][3]);
        }
    }
    __syncthreads();

    // ---- L1 tails at 289 cone slots, spread: 4 lanes per slot, 4 edges each ----
#pragma unroll
    for (int it = 0; it < 2; ++it) {
        const int slot = (it == 0) ? (tid >> 2) : 256 + (tid >> 2);
        const bool act = (it == 0) ? (slot < 256) : (tid < 132);
        if (act) {
            const int chunk = tid & 3;
            const int node = conen[slot];
            float4 hn4 = h1lds[node];
            float hh[4] = {hn4.x, hn4.y, hn4.z, hn4.w};
            float q2[4];
            {
                const float* wq = Wq + 16; const float* bql = bq + 4;
#pragma unroll
                for (int j = 0; j < 4; ++j) {
                    float sq = bql[j];
#pragma unroll
                    for (int i = 0; i < 4; ++i) sq += hh[i] * wq[i * 4 + j];
                    q2[j] = sq * LOG2E;
                }
            }
            int4 s4 = reinterpret_cast<const int4*>(src + node * DEG)[chunk];
            int sis[4] = {s4.x, s4.y, s4.z, s4.w};
            float z[4] = {0.f, 0.f, 0.f, 0.f}, wa[4] = {0.f, 0.f, 0.f, 0.f};
#pragma unroll
            for (int e = 0; e < 4; ++e) {
                uint4 t = kvbuf[sis[e]];
                float p;
                p = __builtin_amdgcn_exp2f(q2[0] * lo_bf(t.x)); z[0] += p; wa[0] += p * lo_bf(t.z);
                p = __builtin_amdgcn_exp2f(q2[1] * hi_bf(t.x)); z[1] += p; wa[1] += p * hi_bf(t.z);
                p = __builtin_amdgcn_exp2f(q2[2] * lo_bf(t.y)); z[2] += p; wa[2] += p * lo_bf(t.w);
                p = __builtin_amdgcn_exp2f(q2[3] * hi_bf(t.y)); z[3] += p; wa[3] += p * hi_bf(t.w);
            }
            // combine across the 4 chunk lanes (bits 0-1 of lane id)
#pragma unroll
            for (int m = 1; m <= 2; m <<= 1) {
#pragma unroll
                for (int j = 0; j < 4; ++j) {
                    z[j]  += __shfl_xor(z[j], m, 64);
                    wa[j] += __shfl_xor(wa[j], m, 64);
                }
            }
            if (chunk == 0) {
                float msg[4];
#pragma unroll
                for (int j = 0; j < 4; ++j) msg[j] = wa[j] * frcp(z[j] + 1e-6f);
                node_tail(hh, msg, Wo + 16, bo + 4, ln1_g + 4, ln1_b + 4,
                          W1 + 32, b1 + 8, W2 + 32, b2 + 4, ln2_g + 4, ln2_b + 4);
#pragma unroll
                for (int j = 0; j < 4; ++j) h2c[slot][j] = hh[j];
            }
        }
    }
    __syncthreads();

    // ---- L2 tails for the 17 C2 nodes (on-demand f32 k/v) ----
    if (tid < 272) {
        const int i = tid >> 4, e = tid & 15;
        const int l2 = 2;
        float q2[4];
        {
            const float* wq = Wq + l2 * 16; const float* bql = bq + l2 * 4;
#pragma unroll
            for (int j = 0; j < 4; ++j) {
                float sq = bql[j];
#pragma unroll
                for (int k = 0; k < 4; ++k) sq += h2c[i][k] * wq[k * 4 + j];
                q2[j] = sq * LOG2E;
            }
        }
        const float* hnb = h2c[17 + tid];
        float z[4], pv[4];
        {
            const float* wk = Wk + l2 * 16; const float* bkl = bk + l2 * 4;
            const float* wv = Wv + l2 * 16; const float* bvl = bv + l2 * 4;
#pragma unroll
            for (int j = 0; j < 4; ++j) {
                float kh = bkl[j], vh = bvl[j];
#pragma unroll
                for (int k = 0; k < 4; ++k) {
                    kh += hnb[k] * wk[k * 4 + j];
                    vh += hnb[k] * wv[k * 4 + j];
                }
                float p = __builtin_amdgcn_exp2f(q2[j] * kh);
                z[j] = p; pv[j] = p * vh;
            }
        }
#pragma unroll
        for (int m = 1; m <= 8; m <<= 1) {
#pragma unroll
            for (int j = 0; j < 4; ++j) {
                z[j]  += __shfl_xor(z[j], m, 64);
                pv[j] += __shfl_xor(pv[j], m, 64);
            }
        }
        if (e == 0) {
            float msg[4];
#pragma unroll
            for (int j = 0; j < 4; ++j) msg[j] = pv[j] * frcp(z[j] + 1e-6f);
            float hh[4] = {h2c[i][0], h2c[i][1], h2c[i][2], h2c[i][3]};
            node_tail(hh, msg, Wo + l2 * 16, bo + l2 * 4, ln1_g + l2 * 4, ln1_b + l2 * 4,
                      W1 + l2 * 32, b1 + l2 * 8, W2 + l2 * 32, b2 + l2 * 4,
                      ln2_g + l2 * 4, ln2_b + l2 * 4);
#pragma unroll
            for (int j = 0; j < 4; ++j) h3buf[i][j] = hh[j];
        }
    }
    __syncthreads();

    // ---- L3 at the agent (wave 0) -> gat_out ----
    if (tid < 64) {
        const int e = tid >> 2, hd = tid & 3;
        const int l3 = 3;
        float ha[4] = {h3buf[16][0], h3buf[16][1], h3buf[16][2], h3buf[16][3]};
        float qh;
        {
            const float* wq = Wq + l3 * 16;
            qh = bq[l3 * 4 + hd];
#pragma unroll
            for (int i = 0; i < 4; ++i) qh += ha[i] * wq[i * 4 + hd];
            qh *= LOG2E;
        }
        float kh, vh;
        {
            const float* wk3 = Wk + l3 * 16; const float* wv3 = Wv + l3 * 16;
            kh = bk[l3 * 4 + hd]; vh = bv[l3 * 4 + hd];
#pragma unroll
            for (int i = 0; i < 4; ++i) {
                kh += h3buf[e][i] * wk3[i * 4 + hd];
                vh += h3buf[e][i] * wv3[i * 4 + hd];
            }
        }
        float p = __builtin_amdgcn_exp2f(qh * kh);
        float z = p, wv_s = p * vh;
#pragma unroll
        for (int m = 4; m <= 32; m <<= 1) {
            z    += __shfl_xor(z, m, 64);
            wv_s += __shfl_xor(wv_s, m, 64);
        }
        float msg_h = wv_s * frcp(z + 1e-6f);
        float msg[4];
#pragma unroll
        for (int j = 0; j < 4; ++j) msg[j] = __shfl(msg_h, (tid & ~3) + j, 64);

        float hh[4] = {ha[0], ha[1], ha[2], ha[3]};
        node_tail(hh, msg, Wo + l3 * 16, bo + l3 * 4, ln1_g + l3 * 4, ln1_b + l3 * 4,
                  W1 + l3 * 32, b1 + l3 * 8, W2 + l3 * 32, b2 + l3 * 4,
                  ln2_g + l3 * 4, ln2_b + l3 * 4);
        if (tid == 0) {
#pragma unroll
            for (int j = 0; j < 4; ++j) gat_out[b * 4 + j] = hh[j];
        }
    }
    __builtin_amdgcn_s_setprio(0);
}

// ===== K2: MLP head (also the fallback mlp2) =====
__global__ __launch_bounds__(64) void mlp2_kernel(
    const float* __restrict__ partial, const float* __restrict__ gat,
    const float* __restrict__ oW1, const float* __restrict__ ob1,
    const float* __restrict__ oW2, const float* __restrict__ ob2,
    const float* __restrict__ oW3, const float* __restrict__ ob3,
    float* __restrict__ out)
{
    __shared__ float hm1[HID], hm2[HID];
    const int b = blockIdx.x;
    const int tid = threadIdx.x;
    if (tid < HID) {
        float s = ob1[tid];
        const float* pp = partial + (size_t)b * KS * HID + tid;
#pragma unroll
        for (int ks = 0; ks < KS; ++ks) s += pp[ks * HID];
#pragma unroll
        for (int k = 0; k < 4; ++k) s += gat[b * 4 + k] * oW1[k * HID + tid];
        hm1[tid] = tanhf(s);
    }
    __syncthreads();
    if (tid < HID) {
        float s = ob2[tid];
        for (int k = 0; k < HID; ++k) s += hm1[k] * oW2[k * HID + tid];
        hm2[tid] = tanhf(s);
    }
    __syncthreads();
    if (tid < NOUT) {
        float s = ob3[tid];
        for (int k = 0; k < HID; ++k) s += hm2[k] * oW3[k * NOUT + tid];
        out[(size_t)b * NOUT + tid] = s;
    }
}

// ===================== fallback path (small ws) =====================
__global__ __launch_bounds__(1024) void gat_single_kernel(
    const float* __restrict__ x, const int* __restrict__ src,
    const int* __restrict__ agent_nodes,
    const float* __restrict__ We, const float* __restrict__ be,
    const float* __restrict__ Wq, const float* __restrict__ bq,
    const float* __restrict__ Wk, const float* __restrict__ bk,
    const float* __restrict__ Wv, const float* __restrict__ bv,
    const float* __restrict__ Wo, const float* __restrict__ bo,
    const float* __restrict__ ln1_g, const float* __restrict__ ln1_b,
    const float* __restrict__ W1, const float* __restrict__ b1,
    const float* __restrict__ W2, const float* __restrict__ b2,
    const float* __restrict__ ln2_g, const float* __restrict__ ln2_b,
    float* __restrict__ gat_out)
{
    __shared__ uint4 kv[NN];
    const int b = blockIdx.x;
    const int tid = threadIdx.x;
    float h[2][4];
#pragma unroll
    for (int u = 0; u < 2; ++u) {
        const int n = tid + u * 1024;
        const float4* xr = reinterpret_cast<const float4*>(x + ((size_t)b * NN + n) * EMBD);
        float xv[16];
#pragma unroll
        for (int t4 = 0; t4 < 4; ++t4) {
            float4 t = xr[t4];
            xv[t4 * 4 + 0] = t.x; xv[t4 * 4 + 1] = t.y;
            xv[t4 * 4 + 2] = t.z; xv[t4 * 4 + 3] = t.w;
        }
#pragma unroll
        for (int j = 0; j < 4; ++j) {
            float s = be[j];
#pragma unroll
            for (int i = 0; i < 16; ++i) s += xv[i] * We[i * 4 + j];
            h[u][j] = s;
        }
    }
    for (int l = 0; l < NL; ++l) {
        float q2[2][4];
        const float* wq = Wq + l * 16; const float* bql = bq + l * 4;
        const float* wk = Wk + l * 16; const float* bkl = bk + l * 4;
        const float* wv = Wv + l * 16; const float* bvl = bv + l * 4;
#pragma unroll
        for (int u = 0; u < 2; ++u) {
            const int n = tid + u * 1024;
#pragma unroll
            for (int j = 0; j < 4; ++j) {
                float sq = bql[j];
#pragma unroll
                for (int i = 0; i < 4; ++i) sq += h[u][i] * wq[i * 4 + j];
                q2[u][j] = sq * LOG2E;
            }
            kv[n] = kv_pack(h[u], wk, bkl, wv, bvl);
        }
        __syncthreads();
#pragma unroll
        for (int u = 0; u < 2; ++u) {
            const int n = tid + u * 1024;
            int su[16];
            const int4* sp = reinterpret_cast<const int4*>(src + n * DEG);
#pragma unroll
            for (int t4 = 0; t4 < 4; ++t4) {
                int4 s4 = sp[t4];
                su[t4 * 4 + 0] = s4.x; su[t4 * 4 + 1] = s4.y;
                su[t4 * 4 + 2] = s4.z; su[t4 * 4 + 3] = s4.w;
            }
            gather_tail(kv, su, q2[u], h[u], l, Wo, bo, ln1_g, ln1_b,
                        W1, b1, W2, b2, ln2_g, ln2_b);
        }
        __syncthreads();
    }
    const int agent = agent_nodes[b];
#pragma unroll
    for (int u = 0; u < 2; ++u) {
        if (tid + u * 1024 == agent) {
#pragma unroll
            for (int j = 0; j < 4; ++j) gat_out[b * 4 + j] = h[u][j];
        }
    }
}

__global__ __launch_bounds__(1024) void mlp1_fb_kernel(
    const float* __restrict__ obs, const float* __restrict__ oW1,
    float* __restrict__ partial)
{
    __shared__ float red[16 * RPB * HID];
    mlp1_block(blockIdx.x, threadIdx.x, obs, oW1, partial, red);
}

extern "C" void kernel_launch(void* const* d_in, const int* in_sizes, int n_in,
                              void* d_out, int out_size, void* d_ws, size_t ws_size,
                              hipStream_t stream) {
    const float* x      = (const float*)d_in[0];
    const float* obs    = (const float*)d_in[1];
    const int*   src    = (const int*)d_in[2];
    /* d_in[3] = dst: structurally repeat(arange(N), DEG) — not needed */
    const int*   agent  = (const int*)d_in[4];
    const float* We     = (const float*)d_in[5];
    const float* be     = (const float*)d_in[6];
    const float* Wq     = (const float*)d_in[7];
    const float* bq     = (const float*)d_in[8];
    const float* Wk     = (const float*)d_in[9];
    const float* bk     = (const float*)d_in[10];
    const float* Wv     = (const float*)d_in[11];
    const float* bv     = (const float*)d_in[12];
    const float* Wo     = (const float*)d_in[13];
    const float* bo     = (const float*)d_in[14];
    const float* ln1_g  = (const float*)d_in[15];
    const float* ln1_b  = (const float*)d_in[16];
    const float* W1     = (const float*)d_in[17];
    const float* b1     = (const float*)d_in[18];
    const float* W2     = (const float*)d_in[19];
    const float* b2     = (const float*)d_in[20];
    const float* ln2_g  = (const float*)d_in[21];
    const float* ln2_b  = (const float*)d_in[22];
    const float* oW1    = (const float*)d_in[23];
    const float* ob1    = (const float*)d_in[24];
    const float* oW2    = (const float*)d_in[25];
    const float* ob2    = (const float*)d_in[26];
    const float* oW3    = (const float*)d_in[27];
    const float* ob3    = (const float*)d_in[28];

    float* out = (float*)d_out;
    char*  ws  = (char*)d_ws;

    float* gat_out = (float*)ws;                 // [128][4]
    float* partial = (float*)(ws + 2048);        // [128][16][45]
    const size_t need = 2048 + 368640;

    if (ws_size >= need) {
        fused_kernel<<<MEGAB + MLPB, 1024, 0, stream>>>(x, src, agent, obs, oW1,
            partial, gat_out,
            We, be, Wq, bq, Wk, bk, Wv, bv, Wo, bo, ln1_g, ln1_b, W1, b1, W2, b2,
            ln2_g, ln2_b);
        mlp2_kernel<<<NB, 64, 0, stream>>>(partial, gat_out, oW1, ob1, oW2, ob2,
                                           oW3, ob3, out);
    } else {
        gat_single_kernel<<<NB, 1024, 0, stream>>>(x, src, agent, We, be, Wq, bq, Wk, bk,
                                                   Wv, bv, Wo, bo, ln1_g, ln1_b, W1, b1,
                                                   W2, b2, ln2_g, ln2_b, gat_out);
        mlp1_fb_kernel<<<MLPB, 1024, 0, stream>>>(obs, oW1, partial);
        mlp2_kernel<<<NB, 64, 0, stream>>>(partial, gat_out, oW1, ob1, oW2, ob2,
                                           oW3, ob3, out);
    }
}

// Round 18
// 29.076 us; speedup vs baseline: 1.0325x; 1.0325x over previous
//
#include <hip/hip_runtime.h>
#include <hip/hip_bf16.h>

#define NB 128
#define NN 2048
#define DEG 16
#define EMBD 16
#define NL 4
#define OBSD 6154
#define HID 45
#define NOUT 15
#define KS 16
#define CH 385   // ceil(OBSD / KS)
#define RPB 8    // batch rows per mlp1 block (share each oW1 load across 8 rows)
#define LOG2E 1.44269504f
#define MEGAB NB                 // 128 mega blocks (1 per graph)
#define MLPB ((NB / RPB) * KS)   // 256 mlp blocks

__device__ __forceinline__ float frcp(float v) { return __builtin_amdgcn_rcpf(v); }

__device__ __forceinline__ uint32_t pk_bf16(float a, float b) {
    uint32_t ua = __float_as_uint(a); ua += 0x7fffu + ((ua >> 16) & 1u);
    uint32_t ub = __float_as_uint(b); ub += 0x7fffu + ((ub >> 16) & 1u);
    return (ua >> 16) | (ub & 0xffff0000u);
}
__device__ __forceinline__ float lo_bf(uint32_t u) { return __uint_as_float(u << 16); }
__device__ __forceinline__ float hi_bf(uint32_t u) { return __uint_as_float(u & 0xffff0000u); }

__device__ __forceinline__ void ln4(const float* p, const float* g, const float* bb, float* o) {
    float m = 0.25f * (p[0] + p[1] + p[2] + p[3]);
    float var = 0.f;
#pragma unroll
    for (int j = 0; j < 4; ++j) { float d = p[j] - m; var += d * d; }
    var *= 0.25f;
    float rs = rsqrtf(var + 1e-5f);
#pragma unroll
    for (int j = 0; j < 4; ++j) o[j] = g[j] * (p[j] - m) * rs + bb[j];
}

__device__ __forceinline__ void node_tail(float* hh, const float* msg,
    const float* wo, const float* bol, const float* g1, const float* be1,
    const float* w1, const float* b1l, const float* w2, const float* b2l,
    const float* g2, const float* be2)
{
    float pre[4];
#pragma unroll
    for (int j = 0; j < 4; ++j) {
        float s = bol[j];
#pragma unroll
        for (int i = 0; i < 4; ++i) s += msg[i] * wo[i * 4 + j];
        pre[j] = hh[j] + s;
    }
    float hn[4];
    ln4(pre, g1, be1, hn);
    float mid[8];
#pragma unroll
    for (int j = 0; j < 8; ++j) {
        float s = b1l[j];
#pragma unroll
        for (int i = 0; i < 4; ++i) s += hn[i] * w1[i * 8 + j];
        mid[j] = fmaxf(s, 0.f);
    }
    float pre2[4];
#pragma unroll
    for (int j = 0; j < 4; ++j) {
        float s = b2l[j];
#pragma unroll
        for (int i = 0; i < 8; ++i) s += mid[i] * w2[i * 4 + j];
        pre2[j] = hn[j] + s;
    }
    ln4(pre2, g2, be2, hh);
}

__device__ __forceinline__ uint4 kv_pack(const float* hh,
    const float* wk, const float* bkl, const float* wv, const float* bvl)
{
    float kk[4], vv[4];
#pragma unroll
    for (int j = 0; j < 4; ++j) {
        float sk = bkl[j], sv = bvl[j];
#pragma unroll
        for (int i = 0; i < 4; ++i) {
            sk += hh[i] * wk[i * 4 + j];
            sv += hh[i] * wv[i * 4 + j];
        }
        kk[j] = sk; vv[j] = sv;
    }
    return make_uint4(pk_bf16(kk[0], kk[1]), pk_bf16(kk[2], kk[3]),
                      pk_bf16(vv[0], vv[1]), pk_bf16(vv[2], vv[3]));
}

// gather + tail body for a layer (kv staged in LDS, q2 prescaled), 16 edges
__device__ __forceinline__ void gather_tail(const uint4* kv, const int* su,
    const float* q2, float* hh, int l,
    const float* Wo, const float* bo, const float* ln1_g, const float* ln1_b,
    const float* W1, const float* b1, const float* W2, const float* b2,
    const float* ln2_g, const float* ln2_b)
{
    float z[4] = {0.f, 0.f, 0.f, 0.f}, wa[4] = {0.f, 0.f, 0.f, 0.f};
#pragma unroll
    for (int eb = 0; eb < 4; ++eb) {
        uint4 t0 = kv[su[eb * 4 + 0]];
        uint4 t1 = kv[su[eb * 4 + 1]];
        uint4 t2 = kv[su[eb * 4 + 2]];
        uint4 t3 = kv[su[eb * 4 + 3]];
        float p;
        p = __builtin_amdgcn_exp2f(q2[0] * lo_bf(t0.x)); z[0] += p; wa[0] += p * lo_bf(t0.z);
        p = __builtin_amdgcn_exp2f(q2[1] * hi_bf(t0.x)); z[1] += p; wa[1] += p * hi_bf(t0.z);
        p = __builtin_amdgcn_exp2f(q2[2] * lo_bf(t0.y)); z[2] += p; wa[2] += p * lo_bf(t0.w);
        p = __builtin_amdgcn_exp2f(q2[3] * hi_bf(t0.y)); z[3] += p; wa[3] += p * hi_bf(t0.w);
        p = __builtin_amdgcn_exp2f(q2[0] * lo_bf(t1.x)); z[0] += p; wa[0] += p * lo_bf(t1.z);
        p = __builtin_amdgcn_exp2f(q2[1] * hi_bf(t1.x)); z[1] += p; wa[1] += p * hi_bf(t1.z);
        p = __builtin_amdgcn_exp2f(q2[2] * lo_bf(t1.y)); z[2] += p; wa[2] += p * lo_bf(t1.w);
        p = __builtin_amdgcn_exp2f(q2[3] * hi_bf(t1.y)); z[3] += p; wa[3] += p * hi_bf(t1.w);
        p = __builtin_amdgcn_exp2f(q2[0] * lo_bf(t2.x)); z[0] += p; wa[0] += p * lo_bf(t2.z);
        p = __builtin_amdgcn_exp2f(q2[1] * hi_bf(t2.x)); z[1] += p; wa[1] += p * hi_bf(t2.z);
        p = __builtin_amdgcn_exp2f(q2[2] * lo_bf(t2.y)); z[2] += p; wa[2] += p * lo_bf(t2.w);
        p = __builtin_amdgcn_exp2f(q2[3] * hi_bf(t2.y)); z[3] += p; wa[3] += p * hi_bf(t2.w);
        p = __builtin_amdgcn_exp2f(q2[0] * lo_bf(t3.x)); z[0] += p; wa[0] += p * lo_bf(t3.z);
        p = __builtin_amdgcn_exp2f(q2[1] * hi_bf(t3.x)); z[1] += p; wa[1] += p * hi_bf(t3.z);
        p = __builtin_amdgcn_exp2f(q2[2] * lo_bf(t3.y)); z[2] += p; wa[2] += p * lo_bf(t3.w);
        p = __builtin_amdgcn_exp2f(q2[3] * hi_bf(t3.y)); z[3] += p; wa[3] += p * hi_bf(t3.w);
    }
    float msg[4];
#pragma unroll
    for (int j = 0; j < 4; ++j) msg[j] = wa[j] * frcp(z[j] + 1e-6f);
    node_tail(hh, msg, Wo + l * 16, bo + l * 4, ln1_g + l * 4, ln1_b + l * 4,
              W1 + l * 32, b1 + l * 8, W2 + l * 32, b2 + l * 4,
              ln2_g + l * 4, ln2_b + l * 4);
}

// mlp1 split-K block body (1024 threads, 16 waves); red = [16][RPB][HID] floats (23 KB)
__device__ __forceinline__ void mlp1_block(int mb, int tid,
    const float* __restrict__ obs, const float* __restrict__ oW1,
    float* __restrict__ partial, float* red)
{
    const int rg = mb >> 4;
    const int ks = mb & (KS - 1);
    const int w = tid >> 6, lane = tid & 63;
    const int c0 = ks * CH;
    const int c1 = min(c0 + CH, OBSD);
    const int wl = (c1 - c0 + 15) >> 4;
    const int s0 = c0 + w * wl;
    const int s1 = min(s0 + wl, c1);
    const float* ob0 = obs + (size_t)(rg * RPB) * OBSD;

    if (lane < HID) {
        float acc[RPB] = {0.f, 0.f, 0.f, 0.f, 0.f, 0.f, 0.f, 0.f};
        for (int i = s0; i < s1; ++i) {
            float wv = oW1[(size_t)(i + 4) * HID + lane];
#pragma unroll
            for (int r = 0; r < RPB; ++r)
                acc[r] += ob0[(size_t)r * OBSD + i] * wv;
        }
#pragma unroll
        for (int r = 0; r < RPB; ++r) red[(w * RPB + r) * HID + lane] = acc[r];
    }
    __syncthreads();
    for (int idx = tid; idx < RPB * HID; idx += 1024) {
        const int r = idx / HID, j = idx % HID;
        float s = 0.f;
#pragma unroll
        for (int ww = 0; ww < 16; ++ww) s += red[(ww * RPB + r) * HID + j];
        partial[(size_t)((rg * RPB + r) * KS + ks) * HID + j] = s;
    }
}

// ===== K1: blocks [0,128): full GAT per graph in LDS; [128,384): mlp1 split-K =====
__global__ __launch_bounds__(1024) void fused_kernel(
    const float* __restrict__ x, const int* __restrict__ src,
    const int* __restrict__ agent_nodes,
    const float* __restrict__ obs, const float* __restrict__ oW1,
    float* __restrict__ partial, float* __restrict__ gat_out,
    const float* __restrict__ We, const float* __restrict__ be,
    const float* __restrict__ Wq, const float* __restrict__ bq,
    const float* __restrict__ Wk, const float* __restrict__ bk,
    const float* __restrict__ Wv, const float* __restrict__ bv,
    const float* __restrict__ Wo, const float* __restrict__ bo,
    const float* __restrict__ ln1_g, const float* __restrict__ ln1_b,
    const float* __restrict__ W1, const float* __restrict__ b1,
    const float* __restrict__ W2, const float* __restrict__ b2,
    const float* __restrict__ ln2_g, const float* __restrict__ ln2_b)
{
    __shared__ uint4  kvbuf[NN];      // 32 KB: kv0, then reused as kv1. mlp: red overlay
    __shared__ float4 h1lds[NN];      // 32 KB
    __shared__ int    conen[289];
    __shared__ float  h2c[289][4];
    __shared__ float  h3buf[17][4];
    const int bid = blockIdx.x;
    const int tid = threadIdx.x;

    if (bid >= MEGAB) {
        mlp1_block(bid - MEGAB, tid, obs, oW1, partial,
                   reinterpret_cast<float*>(kvbuf));
        return;
    }

    // mega block = the critical path; bias the CU scheduler toward these waves
    __builtin_amdgcn_s_setprio(1);

    const int b = bid;
    const int ag = agent_nodes[b];

    // cone node list (only needs src)
    if (tid < 17)  conen[tid] = (tid < 16) ? src[ag * DEG + tid] : ag;
    if (tid < 272) {
        const int i = tid >> 4, e = tid & 15;
        const int ti = (i < 16) ? src[ag * DEG + i] : ag;
        conen[17 + tid] = src[ti * DEG + e];
    }

    // ---- embed both owned nodes, kv0 -> LDS ----
    float he[2][4];
#pragma unroll
    for (int c = 0; c < 2; ++c) {
        const int n = c * 1024 + tid;
        const float4* xr = reinterpret_cast<const float4*>(
            x + ((size_t)b * NN + n) * EMBD);
        float xv[16];
#pragma unroll
        for (int t4 = 0; t4 < 4; ++t4) {
            float4 t = xr[t4];
            xv[t4 * 4 + 0] = t.x; xv[t4 * 4 + 1] = t.y;
            xv[t4 * 4 + 2] = t.z; xv[t4 * 4 + 3] = t.w;
        }
#pragma unroll
        for (int j = 0; j < 4; ++j) {
            float s = be[j];
#pragma unroll
            for (int i = 0; i < 16; ++i) s += xv[i] * We[i * 4 + j];
            he[c][j] = s;
        }
        kvbuf[n] = kv_pack(he[c], Wk, bk, Wv, bv);   // layer-0 weights
    }
    __syncthreads();

    // ---- L0 for both nodes (h1 into registers) ----
    float h1r[2][4];
#pragma unroll
    for (int u = 0; u < 2; ++u) {
        const int n = u * 1024 + tid;
        float q2[4];
#pragma unroll
        for (int j = 0; j < 4; ++j) {
            float sq = bq[j];
#pragma unroll
            for (int i = 0; i < 4; ++i) sq += he[u][i] * Wq[i * 4 + j];
            q2[j] = sq * LOG2E;
        }
        int su[16];
        const int4* sp = reinterpret_cast<const int4*>(src + n * DEG);
#pragma unroll
        for (int t4 = 0; t4 < 4; ++t4) {
            int4 s4 = sp[t4];
            su[t4 * 4 + 0] = s4.x; su[t4 * 4 + 1] = s4.y;
            su[t4 * 4 + 2] = s4.z; su[t4 * 4 + 3] = s4.w;
        }
        float hh[4] = {he[u][0], he[u][1], he[u][2], he[u][3]};
        gather_tail(kvbuf, su, q2, hh, 0, Wo, bo, ln1_g, ln1_b, W1, b1, W2, b2,
                    ln2_g, ln2_b);
#pragma unroll
        for (int j = 0; j < 4; ++j) h1r[u][j] = hh[j];
    }
    __syncthreads();   // all L0 gathers done -> safe to overwrite kvbuf

    // ---- kv1 overwrites kvbuf; h1 -> LDS ----
    {
        const float* wk1 = Wk + 16; const float* bk1 = bk + 4;
        const float* wv1 = Wv + 16; const float* bv1 = bv + 4;
#pragma unroll
        for (int u = 0; u < 2; ++u) {
            const int n = u * 1024 + tid;
            kvbuf[n] = kv_pack(h1r[u], wk1, bk1, wv1, bv1);
            h1lds[n] = make_float4(h1r[u][0], h1r[u][1], h1r[u][2], h1r[u][3]);
        }
    }
    __syncthreads();

    // ---- L1 tails at 289 cone slots ----
    if (tid < 289) {
        const int node = conen[tid];
        float4 hn4 = h1lds[node];
        float hh[4] = {hn4.x, hn4.y, hn4.z, hn4.w};
        float q2[4];
        {
            const float* wq = Wq + 16; const float* bql = bq + 4;
#pragma unroll
            for (int j = 0; j < 4; ++j) {
                float sq = bql[j];
#pragma unroll
                for (int i = 0; i < 4; ++i) sq += hh[i] * wq[i * 4 + j];
                q2[j] = sq * LOG2E;
            }
        }
        int su2[16];
        const int4* sp = reinterpret_cast<const int4*>(src + node * DEG);
#pragma unroll
        for (int t4 = 0; t4 < 4; ++t4) {
            int4 s4 = sp[t4];
            su2[t4 * 4 + 0] = s4.x; su2[t4 * 4 + 1] = s4.y;
            su2[t4 * 4 + 2] = s4.z; su2[t4 * 4 + 3] = s4.w;
        }
        gather_tail(kvbuf, su2, q2, hh, 1, Wo, bo, ln1_g, ln1_b, W1, b1, W2, b2,
                    ln2_g, ln2_b);
#pragma unroll
        for (int j = 0; j < 4; ++j) h2c[tid][j] = hh[j];
    }
    __syncthreads();

    // ---- L2 tails for the 17 C2 nodes (on-demand f32 k/v) ----
    if (tid < 272) {
        const int i = tid >> 4, e = tid & 15;
        const int l2 = 2;
        float q2[4];
        {
            const float* wq = Wq + l2 * 16; const float* bql = bq + l2 * 4;
#pragma unroll
            for (int j = 0; j < 4; ++j) {
                float sq = bql[j];
#pragma unroll
                for (int k = 0; k < 4; ++k) sq += h2c[i][k] * wq[k * 4 + j];
                q2[j] = sq * LOG2E;
            }
        }
        const float* hnb = h2c[17 + tid];
        float z[4], pv[4];
        {
            const float* wk = Wk + l2 * 16; const float* bkl = bk + l2 * 4;
            const float* wv = Wv + l2 * 16; const float* bvl = bv + l2 * 4;
#pragma unroll
            for (int j = 0; j < 4; ++j) {
                float kh = bkl[j], vh = bvl[j];
#pragma unroll
                for (int k = 0; k < 4; ++k) {
                    kh += hnb[k] * wk[k * 4 + j];
                    vh += hnb[k] * wv[k * 4 + j];
                }
                float p = __builtin_amdgcn_exp2f(q2[j] * kh);
                z[j] = p; pv[j] = p * vh;
            }
        }
#pragma unroll
        for (int m = 1; m <= 8; m <<= 1) {
#pragma unroll
            for (int j = 0; j < 4; ++j) {
                z[j]  += __shfl_xor(z[j], m, 64);
                pv[j] += __shfl_xor(pv[j], m, 64);
            }
        }
        if (e == 0) {
            float msg[4];
#pragma unroll
            for (int j = 0; j < 4; ++j) msg[j] = pv[j] * frcp(z[j] + 1e-6f);
            float hh[4] = {h2c[i][0], h2c[i][1], h2c[i][2], h2c[i][3]};
            node_tail(hh, msg, Wo + l2 * 16, bo + l2 * 4, ln1_g + l2 * 4, ln1_b + l2 * 4,
                      W1 + l2 * 32, b1 + l2 * 8, W2 + l2 * 32, b2 + l2 * 4,
                      ln2_g + l2 * 4, ln2_b + l2 * 4);
#pragma unroll
            for (int j = 0; j < 4; ++j) h3buf[i][j] = hh[j];
        }
    }
    __syncthreads();

    // ---- L3 at the agent (wave 0) -> gat_out ----
    if (tid < 64) {
        const int e = tid >> 2, hd = tid & 3;
        const int l3 = 3;
        float ha[4] = {h3buf[16][0], h3buf[16][1], h3buf[16][2], h3buf[16][3]};
        float qh;
        {
            const float* wq = Wq + l3 * 16;
            qh = bq[l3 * 4 + hd];
#pragma unroll
            for (int i = 0; i < 4; ++i) qh += ha[i] * wq[i * 4 + hd];
            qh *= LOG2E;
        }
        float kh, vh;
        {
            const float* wk3 = Wk + l3 * 16; const float* wv3 = Wv + l3 * 16;
            kh = bk[l3 * 4 + hd]; vh = bv[l3 * 4 + hd];
#pragma unroll
            for (int i = 0; i < 4; ++i) {
                kh += h3buf[e][i] * wk3[i * 4 + hd];
                vh += h3buf[e][i] * wv3[i * 4 + hd];
            }
        }
        float p = __builtin_amdgcn_exp2f(qh * kh);
        float z = p, wv_s = p * vh;
#pragma unroll
        for (int m = 4; m <= 32; m <<= 1) {
            z    += __shfl_xor(z, m, 64);
            wv_s += __shfl_xor(wv_s, m, 64);
        }
        float msg_h = wv_s * frcp(z + 1e-6f);
        float msg[4];
#pragma unroll
        for (int j = 0; j < 4; ++j) msg[j] = __shfl(msg_h, (tid & ~3) + j, 64);

        float hh[4] = {ha[0], ha[1], ha[2], ha[3]};
        node_tail(hh, msg, Wo + l3 * 16, bo + l3 * 4, ln1_g + l3 * 4, ln1_b + l3 * 4,
                  W1 + l3 * 32, b1 + l3 * 8, W2 + l3 * 32, b2 + l3 * 4,
                  ln2_g + l3 * 4, ln2_b + l3 * 4);
        if (tid == 0) {
#pragma unroll
            for (int j = 0; j < 4; ++j) gat_out[b * 4 + j] = hh[j];
        }
    }
    __builtin_amdgcn_s_setprio(0);
}

// ===== K2: MLP head (also the fallback mlp2) =====
__global__ __launch_bounds__(64) void mlp2_kernel(
    const float* __restrict__ partial, const float* __restrict__ gat,
    const float* __restrict__ oW1, const float* __restrict__ ob1,
    const float* __restrict__ oW2, const float* __restrict__ ob2,
    const float* __restrict__ oW3, const float* __restrict__ ob3,
    float* __restrict__ out)
{
    __shared__ float hm1[HID], hm2[HID];
    const int b = blockIdx.x;
    const int tid = threadIdx.x;
    if (tid < HID) {
        float s = ob1[tid];
        const float* pp = partial + (size_t)b * KS * HID + tid;
#pragma unroll
        for (int ks = 0; ks < KS; ++ks) s += pp[ks * HID];
#pragma unroll
        for (int k = 0; k < 4; ++k) s += gat[b * 4 + k] * oW1[k * HID + tid];
        hm1[tid] = tanhf(s);
    }
    __syncthreads();
    if (tid < HID) {
        float s = ob2[tid];
        for (int k = 0; k < HID; ++k) s += hm1[k] * oW2[k * HID + tid];
        hm2[tid] = tanhf(s);
    }
    __syncthreads();
    if (tid < NOUT) {
        float s = ob3[tid];
        for (int k = 0; k < HID; ++k) s += hm2[k] * oW3[k * NOUT + tid];
        out[(size_t)b * NOUT + tid] = s;
    }
}

// ===================== fallback path (small ws) =====================
__global__ __launch_bounds__(1024) void gat_single_kernel(
    const float* __restrict__ x, const int* __restrict__ src,
    const int* __restrict__ agent_nodes,
    const float* __restrict__ We, const float* __restrict__ be,
    const float* __restrict__ Wq, const float* __restrict__ bq,
    const float* __restrict__ Wk, const float* __restrict__ bk,
    const float* __restrict__ Wv, const float* __restrict__ bv,
    const float* __restrict__ Wo, const float* __restrict__ bo,
    const float* __restrict__ ln1_g, const float* __restrict__ ln1_b,
    const float* __restrict__ W1, const float* __restrict__ b1,
    const float* __restrict__ W2, const float* __restrict__ b2,
    const float* __restrict__ ln2_g, const float* __restrict__ ln2_b,
    float* __restrict__ gat_out)
{
    __shared__ uint4 kv[NN];
    const int b = blockIdx.x;
    const int tid = threadIdx.x;
    float h[2][4];
#pragma unroll
    for (int u = 0; u < 2; ++u) {
        const int n = tid + u * 1024;
        const float4* xr = reinterpret_cast<const float4*>(x + ((size_t)b * NN + n) * EMBD);
        float xv[16];
#pragma unroll
        for (int t4 = 0; t4 < 4; ++t4) {
            float4 t = xr[t4];
            xv[t4 * 4 + 0] = t.x; xv[t4 * 4 + 1] = t.y;
            xv[t4 * 4 + 2] = t.z; xv[t4 * 4 + 3] = t.w;
        }
#pragma unroll
        for (int j = 0; j < 4; ++j) {
            float s = be[j];
#pragma unroll
            for (int i = 0; i < 16; ++i) s += xv[i] * We[i * 4 + j];
            h[u][j] = s;
        }
    }
    for (int l = 0; l < NL; ++l) {
        float q2[2][4];
        const float* wq = Wq + l * 16; const float* bql = bq + l * 4;
        const float* wk = Wk + l * 16; const float* bkl = bk + l * 4;
        const float* wv = Wv + l * 16; const float* bvl = bv + l * 4;
#pragma unroll
        for (int u = 0; u < 2; ++u) {
            const int n = tid + u * 1024;
#pragma unroll
            for (int j = 0; j < 4; ++j) {
                float sq = bql[j];
#pragma unroll
                for (int i = 0; i < 4; ++i) sq += h[u][i] * wq[i * 4 + j];
                q2[u][j] = sq * LOG2E;
            }
            kv[n] = kv_pack(h[u], wk, bkl, wv, bvl);
        }
        __syncthreads();
#pragma unroll
        for (int u = 0; u < 2; ++u) {
            const int n = tid + u * 1024;
            int su[16];
            const int4* sp = reinterpret_cast<const int4*>(src + n * DEG);
#pragma unroll
            for (int t4 = 0; t4 < 4; ++t4) {
                int4 s4 = sp[t4];
                su[t4 * 4 + 0] = s4.x; su[t4 * 4 + 1] = s4.y;
                su[t4 * 4 + 2] = s4.z; su[t4 * 4 + 3] = s4.w;
            }
            gather_tail(kv, su, q2[u], h[u], l, Wo, bo, ln1_g, ln1_b,
                        W1, b1, W2, b2, ln2_g, ln2_b);
        }
        __syncthreads();
    }
    const int agent = agent_nodes[b];
#pragma unroll
    for (int u = 0; u < 2; ++u) {
        if (tid + u * 1024 == agent) {
#pragma unroll
            for (int j = 0; j < 4; ++j) gat_out[b * 4 + j] = h[u][j];
        }
    }
}

__global__ __launch_bounds__(1024) void mlp1_fb_kernel(
    const float* __restrict__ obs, const float* __restrict__ oW1,
    float* __restrict__ partial)
{
    __shared__ float red[16 * RPB * HID];
    mlp1_block(blockIdx.x, threadIdx.x, obs, oW1, partial, red);
}

extern "C" void kernel_launch(void* const* d_in, const int* in_sizes, int n_in,
                              void* d_out, int out_size, void* d_ws, size_t ws_size,
                              hipStream_t stream) {
    const float* x      = (const float*)d_in[0];
    const float* obs    = (const float*)d_in[1];
    const int*   src    = (const int*)d_in[2];
    /* d_in[3] = dst: structurally repeat(arange(N), DEG) — not needed */
    const int*   agent  = (const int*)d_in[4];
    const float* We     = (const float*)d_in[5];
    const float* be     = (const float*)d_in[6];
    const float* Wq     = (const float*)d_in[7];
    const float* bq     = (const float*)d_in[8];
    const float* Wk     = (const float*)d_in[9];
    const float* bk     = (const float*)d_in[10];
    const float* Wv     = (const float*)d_in[11];
    const float* bv     = (const float*)d_in[12];
    const float* Wo     = (const float*)d_in[13];
    const float* bo     = (const float*)d_in[14];
    const float* ln1_g  = (const float*)d_in[15];
    const float* ln1_b  = (const float*)d_in[16];
    const float* W1     = (const float*)d_in[17];
    const float* b1     = (const float*)d_in[18];
    const float* W2     = (const float*)d_in[19];
    const float* b2     = (const float*)d_in[20];
    const float* ln2_g  = (const float*)d_in[21];
    const float* ln2_b  = (const float*)d_in[22];
    const float* oW1    = (const float*)d_in[23];
    const float* ob1    = (const float*)d_in[24];
    const float* oW2    = (const float*)d_in[25];
    const float* ob2    = (const float*)d_in[26];
    const float* oW3    = (const float*)d_in[27];
    const float* ob3    = (const float*)d_in[28];

    float* out = (float*)d_out;
    char*  ws  = (char*)d_ws;

    float* gat_out = (float*)ws;                 // [128][4]
    float* partial = (float*)(ws + 2048);        // [128][16][45]
    const size_t need = 2048 + 368640;

    if (ws_size >= need) {
        fused_kernel<<<MEGAB + MLPB, 1024, 0, stream>>>(x, src, agent, obs, oW1,
            partial, gat_out,
            We, be, Wq, bq, Wk, bk, Wv, bv, Wo, bo, ln1_g, ln1_b, W1, b1, W2, b2,
            ln2_g, ln2_b);
        mlp2_kernel<<<NB, 64, 0, stream>>>(partial, gat_out, oW1, ob1, oW2, ob2,
                                           oW3, ob3, out);
    } else {
        gat_single_kernel<<<NB, 1024, 0, stream>>>(x, src, agent, We, be, Wq, bq, Wk, bk,
                                                   Wv, bv, Wo, bo, ln1_g, ln1_b, W1, b1,
                                                   W2, b2, ln2_g, ln2_b, gat_out);
        mlp1_fb_kernel<<<MLPB, 1024, 0, stream>>>(obs, oW1, partial);
        mlp2_kernel<<<NB, 64, 0, stream>>>(partial, gat_out, oW1, ob1, oW2, ob2,
                                           oW3, ob3, out);
    }
}